// Round 2
// baseline (114.729 us; speedup 1.0000x reference)
//
#include <hip/hip_runtime.h>

#define HH 256
#define WW 256
#define NPIX (2 * HH * WW)   // 131072 (B=2)
#define NC 48
#define NB 31
#define NG 6          // channel groups
#define CG 8          // channels per group (NG*CG == NC)
#define OT 32         // output tile (32x32 per block)
#define PT 38         // phi tile = OT+6
#define PSTR 44       // phi LDS row stride (16B aligned)
#define UT 44         // u tile = OT+12
#define USTR 52       // u LDS row stride (16B aligned)
#define TP 192        // table pairs per channel: x in [-1.5,1.5], h=1/64

// r16: (1) tnrd_table fused into tnrd_main -- each block builds its 8
// channel tables in LDS (value-once pass through phi_s scratch, then
// (value,delta) pairing). Kills one kernel launch (110us total vs 52us
// main => ~50us is launch/overhead) and the d_out alias. Gathers back
// to LDS (r14/r15 A/B proved LDS==global for the gather: 52.0 vs 52.9).
// (2) ALL hot-path arrays -> named scalars / float4 components (r15
// WRITE_SIZE=30MB vs 3.1MB logical part stores suggests residual
// scratch from av/bv/pha/phb/sv/sa/sb indexed arrays).
// Hard-won constraints (do not violate):
//  - all per-lane accumulators NAMED SCALARS (r3: arrays -> 700 MB spill)
//  - 2 channels/pass, dy loop unroll-pinned (r5: 4ch+unroll -> VALU +40%)
//  - 4-px items, 12-float window (r6: 8-px items -> 300 MB spill)
//  - more blocks/CU does not help (r10); atomic combine is a 34 us loss (r13)
//  - table gather: LDS == global speed (r15); conflict counter tracks
//    structured b128 count, not a fixable serialization (r15 null)

// conv1 inner step: window scalars s0..s3, both channels' weights
#define F1STEP(WI, s0, s1, s2, s3)                                      \
    { float fa = wa[WI], fb = wb[WI];                                   \
      a0 = fmaf(s0, fa, a0); a1 = fmaf(s1, fa, a1);                     \
      a2 = fmaf(s2, fa, a2); a3 = fmaf(s3, fa, a3);                     \
      b0 = fmaf(s0, fb, b0); b1 = fmaf(s1, fb, b1);                     \
      b2 = fmaf(s2, fb, b2); b3 = fmaf(s3, fb, b3); }

// 7 taps over the 10-float window (q0.xyzw q1.xyzw q2.xy), same FMA
// order as the original sv[dx+j] loop
#define F1ROW(WA, WB, q0, q1, q2)                                       \
    { const float* wa = (WA); const float* wb = (WB);                   \
      F1STEP(0, q0.x, q0.y, q0.z, q0.w)                                 \
      F1STEP(1, q0.y, q0.z, q0.w, q1.x)                                 \
      F1STEP(2, q0.z, q0.w, q1.x, q1.y)                                 \
      F1STEP(3, q0.w, q1.x, q1.y, q1.z)                                 \
      F1STEP(4, q1.x, q1.y, q1.z, q1.w)                                 \
      F1STEP(5, q1.y, q1.z, q1.w, q2.x)                                 \
      F1STEP(6, q1.z, q1.w, q2.x, q2.y) }

// table lerp, named temps only
#define LERP1(res, aval, T)                                             \
    { float t_ = fminf(fmaxf(fmaf(aval, 64.f, 96.f), 0.f), 191.999f);   \
      float fj_ = floorf(t_);                                           \
      float2 e_ = (T)[(int)fj_];               /* ds_read_b64 */        \
      res = fmaf(t_ - fj_, e_.y, e_.x); }

// conv2 inner step (flipped weights), both channels, same FMA order
#define C2STEP(WI, s0, s1, s2, s3, t0, t1, t2, t3)                      \
    { float fa = wra[WI], fb = wrb[WI];                                 \
      o0 = fmaf(s0, fa, o0); o1 = fmaf(s1, fa, o1);                     \
      o2 = fmaf(s2, fa, o2); o3 = fmaf(s3, fa, o3);                     \
      o0 = fmaf(t0, fb, o0); o1 = fmaf(t1, fb, o1);                     \
      o2 = fmaf(t2, fb, o2); o3 = fmaf(t3, fb, o3); }

__global__ __launch_bounds__(256, 3)
void tnrd_main(const float* __restrict__ u,
               const float* __restrict__ wf,    // filters [48][49]
               const float* __restrict__ wr,    // rbf weights [48][31]
               float* __restrict__ part)
{
    __shared__ __align__(16) float u_s[UT * USTR];          //  9152 B
    __shared__ __align__(16) float phi_s[4][PT * PSTR];     // 26752 B
    __shared__ __align__(16) float2 tabs[CG][TP];           // 12288 B

    const int tid = threadIdx.x;
    const int bx = blockIdx.x, by = blockIdx.y;
    const int b = blockIdx.z / NG, g = blockIdx.z % NG;
    const int c0g = g * CG;

    // ---- stage u tile (6-halo, zero-padded incl. stride pad) ----
    const int uy0 = by * OT - 6, ux0 = bx * OT - 6;
    const float* ub = u + b * (HH * WW);
    for (int i = tid; i < UT * USTR; i += 256) {
        int r = i / USTR, c = i - r * USTR;
        int gy = uy0 + r, gx = ux0 + c;
        float v = 0.f;
        if (c < UT && (unsigned)gy < HH && (unsigned)gx < WW)
            v = ub[gy * WW + gx];
        u_s[i] = v;
    }

    // ---- build this group's 8 tables in LDS (fused tnrd_table) ----
    // pass 1: raw values at 193 grid points per channel, into phi_s scratch
    float* tv = &phi_s[0][0];                  // 8*193 = 1544 <= 1672 floats
    for (int i = tid; i < CG * (TP + 1); i += 256) {
        int ch = i / (TP + 1), j = i - ch * (TP + 1);
        const float* rc = wr + (c0g + ch) * NB;
        float x = fmaf((float)j, 1.0f / 64.0f, -1.5f);
        float v = 0.f;
        #pragma unroll
        for (int k = 0; k < NB; ++k) {
            float mu = -1.f + (float)k * (1.f / 15.f);
            float d = x - mu;
            v = fmaf(rc[k], __expf(-50.f * d * d), v);
        }
        tv[i] = v;
    }
    __syncthreads();
    // pass 2: (value, delta) pairs for 1-read lerp
    for (int i = tid; i < CG * TP; i += 256) {
        int ch = i / TP, j = i - ch * TP;
        float v0 = tv[ch * (TP + 1) + j];
        float v1 = tv[ch * (TP + 1) + j + 1];
        tabs[ch][j] = make_float2(v0, v1 - v0);
    }
    __syncthreads();   // covers u_s, tabs; phi_s scratch free to reuse

    const int oy = tid >> 3;        // 0..31
    const int ox0 = (tid & 7) * 4;  // 0..28
    float o0 = 0.f, o1 = 0.f, o2 = 0.f, o3 = 0.f;
    const int py0 = by * OT - 3, px0 = bx * OT - 3;

    // ---- conv1 + RBF lerp for channel pair cp into planes bufA/bufB ----
    auto conv1_pass = [&](int cp, float* __restrict__ bufA,
                          float* __restrict__ bufB) {
        const float* wA = wf + (c0g + 2 * cp) * 49;   // block-uniform s_load
        const float* wB = wA + 49;
        const float2* tA = tabs[2 * cp];
        const float2* tB = tabs[2 * cp + 1];
        // 380 items = 10 col-strips x 38 rows (column-major)
        for (int p = 0; p < 2; ++p) {
            const int gi = tid + p * 256;
            if (gi < PT * 10) {
                const int pr = gi % PT, pc = (gi / PT) * 4;
                float a0 = 0.f, a1 = 0.f, a2 = 0.f, a3 = 0.f;
                float b0 = 0.f, b1 = 0.f, b2 = 0.f, b3 = 0.f;
                const float* bptr = &u_s[pr * USTR + pc];

                // software pipeline: load row dy+1 before consuming row dy
                float4 c0 = *(const float4*)(bptr);
                float4 c1 = *(const float4*)(bptr + 4);
                float2 c2 = *(const float2*)(bptr + 8);
                #pragma unroll 1
                for (int dy = 0; dy < 6; ++dy) {
                    const float* nr = bptr + (dy + 1) * USTR;
                    float4 n0 = *(const float4*)(nr);
                    float4 n1 = *(const float4*)(nr + 4);
                    float2 n2 = *(const float2*)(nr + 8);
                    F1ROW(wA + dy * 7, wB + dy * 7, c0, c1, c2)
                    c0 = n0; c1 = n1; c2 = n2;
                }
                F1ROW(wA + 42, wB + 42, c0, c1, c2)   // epilogue dy=6

                // ---- 1-gather lerp, named scalars only;
                //      phi = 0 outside image (conv2 zero-pad) ----
                const int gy = py0 + pr;
                const bool rowok = (unsigned)gy < HH;
                const bool ok0 = rowok && (unsigned)(px0 + pc + 0) < WW;
                const bool ok1 = rowok && (unsigned)(px0 + pc + 1) < WW;
                const bool ok2 = rowok && (unsigned)(px0 + pc + 2) < WW;
                const bool ok3 = rowok && (unsigned)(px0 + pc + 3) < WW;
                float pA0, pA1, pA2, pA3, pB0, pB1, pB2, pB3;
                LERP1(pA0, a0, tA) LERP1(pB0, b0, tB)
                LERP1(pA1, a1, tA) LERP1(pB1, b1, tB)
                LERP1(pA2, a2, tA) LERP1(pB2, b2, tB)
                LERP1(pA3, a3, tA) LERP1(pB3, b3, tB)
                pA0 = ok0 ? pA0 : 0.f;  pB0 = ok0 ? pB0 : 0.f;
                pA1 = ok1 ? pA1 : 0.f;  pB1 = ok1 ? pB1 : 0.f;
                pA2 = ok2 ? pA2 : 0.f;  pB2 = ok2 ? pB2 : 0.f;
                pA3 = ok3 ? pA3 : 0.f;  pB3 = ok3 ? pB3 : 0.f;
                *(float4*)(bufA + pr * PSTR + pc) =
                    make_float4(pA0, pA1, pA2, pA3);      // ds_write_b128
                *(float4*)(bufB + pr * PSTR + pc) =
                    make_float4(pB0, pB1, pB2, pB3);      // ds_write_b128
            }
        }
    };

    // prologue: pass 0 -> planes {0,1}
    conv1_pass(0, phi_s[0], phi_s[1]);
    __syncthreads();

    #pragma unroll 1
    for (int pass = 0; pass < 4; ++pass) {
        if (pass < 3) {
            const int nb_ = (pass + 1) & 1;
            conv1_pass(pass + 1, phi_s[2 * nb_], phi_s[2 * nb_ + 1]);
        }

        // ---- conv2 accumulate pass's two channels (flipped weights) ----
        const float* wA = wf + (c0g + 2 * pass) * 49;
        const float* wB = wA + 49;
        const float* pA = phi_s[2 * (pass & 1)];
        const float* pB = phi_s[2 * (pass & 1) + 1];
        for (int dy = 0; dy < 7; ++dy) {
            const float* rA = pA + (oy + dy) * PSTR + ox0;
            const float* rB = pB + (oy + dy) * PSTR + ox0;
            const float4 A0 = *(const float4*)(rA);
            const float4 A1 = *(const float4*)(rA + 4);
            const float2 A2 = *(const float2*)(rA + 8);
            const float4 B0 = *(const float4*)(rB);
            const float4 B1 = *(const float4*)(rB + 4);
            const float2 B2 = *(const float2*)(rB + 8);
            const float* wra = wA + (6 - dy) * 7;
            const float* wrb = wB + (6 - dy) * 7;
            C2STEP(6, A0.x, A0.y, A0.z, A0.w, B0.x, B0.y, B0.z, B0.w)
            C2STEP(5, A0.y, A0.z, A0.w, A1.x, B0.y, B0.z, B0.w, B1.x)
            C2STEP(4, A0.z, A0.w, A1.x, A1.y, B0.z, B0.w, B1.x, B1.y)
            C2STEP(3, A0.w, A1.x, A1.y, A1.z, B0.w, B1.x, B1.y, B1.z)
            C2STEP(2, A1.x, A1.y, A1.z, A1.w, B1.x, B1.y, B1.z, B1.w)
            C2STEP(1, A1.y, A1.z, A1.w, A2.x, B1.y, B1.z, B1.w, B2.x)
            C2STEP(0, A1.z, A1.w, A2.x, A2.y, B1.z, B1.w, B2.x, B2.y)
        }
        if (pass < 3) __syncthreads();
    }

    const int gy = by * OT + oy, gx = bx * OT + ox0;
    float4 v4 = make_float4(o0, o1, o2, o3);
    *reinterpret_cast<float4*>(part + (size_t)g * NPIX + b * (HH * WW)
                               + gy * WW + gx) = v4;
}

__global__ __launch_bounds__(256)
void combine_kernel(const float* __restrict__ u,
                    const float* __restrict__ f,
                    const float* __restrict__ lam,
                    const float* __restrict__ part,
                    float* __restrict__ out)
{
    int i = blockIdx.x * 256 + threadIdx.x;  // 512 blocks -> NPIX
    float d = 0.f;
    #pragma unroll
    for (int g = 0; g < NG; ++g) d += part[g * NPIX + i];
    float lv = lam[0];
    float uv = u[i];
    float fv = f[i];
    out[i] = uv - d - lv * (uv - fv);
}

extern "C" void kernel_launch(void* const* d_in, const int* in_sizes, int n_in,
                              void* d_out, int out_size, void* d_ws, size_t ws_size,
                              hipStream_t stream) {
    const float* u    = (const float*)d_in[0];
    const float* f    = (const float*)d_in[1];
    const float* filt = (const float*)d_in[2];
    const float* rbfw = (const float*)d_in[3];
    const float* lam  = (const float*)d_in[4];
    float* out = (float*)d_out;
    float* part = (float*)d_ws;   // 6 * 131072 f32 partial sums (3.1 MB)

    tnrd_main<<<dim3(8, 8, 2 * NG), 256, 0, stream>>>(u, filt, rbfw, part);
    combine_kernel<<<512, 256, 0, stream>>>(u, f, lam, part, out);
}

// Round 3
// 99.926 us; speedup vs baseline: 1.1481x; 1.1481x over previous
//
#include <hip/hip_runtime.h>

#define HH 256
#define WW 256
#define NPIX (2 * HH * WW)   // 131072 (B=2)
#define NC 48
#define NB 31
#define OT 32         // output tile (32x32 per block)
#define PT 38         // phi tile = OT+6
#define PSTR 44       // phi LDS row stride (16B aligned, conflict-free)
#define UT 44         // u tile = OT+12
#define USTR 52       // u LDS row stride (16B aligned, conflict-free)
#define TP 192        // table pairs per channel: x in [-1.5,1.5], h=1/64

// r17: occupancy attack. r14/r15/r16 A/B series proved time is invariant
// to gather pipe (LDS vs global) and launch count (~52us harness fixed
// cost outside tnrd_main). Kernel is wave-starved: NG=6 grid = exactly
// 3 blocks/CU = 3 waves/SIMD, barrier-coupled; VALU issue math says ~19K
// cy/SIMD of work vs 125K cy measured. Fix: NG 6->12 (4ch/block, 2
// passes) -> 6 independent blocks/CU. To fit: single-buffered phi (2
// planes, +1 sync), gather from GLOBAL (r15: == LDS speed), no tabs
// staging -> LDS 22.5KB, launch_bounds(256,6) (VGPR cap 85, have 84).
// Separate tnrd_table kernel is back (r16: fusion cost +6.7us VALU,
// launch saving only ~2.5us). part = 12 planes (6.3MB d_ws) with
// ws_size-guarded fallback to the 6-group variant.
// Hard-won constraints (do not violate):
//  - all per-lane accumulators NAMED SCALARS (r3: arrays -> 700 MB spill)
//  - 2 channels/pass, dy loop unroll-pinned (r5: 4ch+unroll -> VALU +40%)
//  - 4-px items, 12-float window (r6: 8-px items -> 300 MB spill)
//  - atomic combine is a 34 us loss (r13)
//  - "more blocks/CU doesn't help" (r10) tested launch_bounds only --
//    the NG=6 grid could never supply >3 blocks/CU; this tests the grid.

// ---- Build the 48 phi tables once as (value, delta) pairs for 1-read lerp.
__global__ __launch_bounds__(256)
void tnrd_table(const float* __restrict__ wr, float2* __restrict__ tab)
{
    const int ch = blockIdx.x;
    const float* rc = wr + ch * NB;
    for (int j = threadIdx.x; j < TP; j += 256) {
        float v0 = 0.f, v1 = 0.f;
        float x0 = fmaf((float)j, 1.0f / 64.0f, -1.5f);
        float x1 = x0 + 1.0f / 64.0f;
        #pragma unroll
        for (int k = 0; k < NB; ++k) {
            float mu = -1.f + (float)k * (1.f / 15.f);
            float d0 = x0 - mu, d1 = x1 - mu;
            float w = rc[k];
            v0 = fmaf(w, __expf(-50.f * d0 * d0), v0);
            v1 = fmaf(w, __expf(-50.f * d1 * d1), v1);
        }
        tab[ch * TP + j] = make_float2(v0, v1 - v0);
    }
}

// conv1 inner step: window scalars s0..s3, both channels' weights
#define F1STEP(WI, s0, s1, s2, s3)                                      \
    { float fa = wa[WI], fb = wb[WI];                                   \
      a0 = fmaf(s0, fa, a0); a1 = fmaf(s1, fa, a1);                     \
      a2 = fmaf(s2, fa, a2); a3 = fmaf(s3, fa, a3);                     \
      b0 = fmaf(s0, fb, b0); b1 = fmaf(s1, fb, b1);                     \
      b2 = fmaf(s2, fb, b2); b3 = fmaf(s3, fb, b3); }

// 7 taps over the 10-float window (q0.xyzw q1.xyzw q2.xy)
#define F1ROW(WA, WB, q0, q1, q2)                                       \
    { const float* wa = (WA); const float* wb = (WB);                   \
      F1STEP(0, q0.x, q0.y, q0.z, q0.w)                                 \
      F1STEP(1, q0.y, q0.z, q0.w, q1.x)                                 \
      F1STEP(2, q0.z, q0.w, q1.x, q1.y)                                 \
      F1STEP(3, q0.w, q1.x, q1.y, q1.z)                                 \
      F1STEP(4, q1.x, q1.y, q1.z, q1.w)                                 \
      F1STEP(5, q1.y, q1.z, q1.w, q2.x)                                 \
      F1STEP(6, q1.z, q1.w, q2.x, q2.y) }

// table lerp from global (L1-resident 18KB table), named temps only
#define LERP1(res, aval, T)                                             \
    { float t_ = fminf(fmaxf(fmaf(aval, 64.f, 96.f), 0.f), 191.999f);   \
      float fj_ = floorf(t_);                                           \
      float2 e_ = (T)[(int)fj_];            /* global_load_dwordx2 */   \
      res = fmaf(t_ - fj_, e_.y, e_.x); }

// conv2 inner step (flipped weights), both channels
#define C2STEP(WI, s0, s1, s2, s3, t0, t1, t2, t3)                      \
    { float fa = wra[WI], fb = wrb[WI];                                 \
      o0 = fmaf(s0, fa, o0); o1 = fmaf(s1, fa, o1);                     \
      o2 = fmaf(s2, fa, o2); o3 = fmaf(s3, fa, o3);                     \
      o0 = fmaf(t0, fb, o0); o1 = fmaf(t1, fb, o1);                     \
      o2 = fmaf(t2, fb, o2); o3 = fmaf(t3, fb, o3); }

template<int CPG>   // channels per group (4 main, 8 fallback)
__global__ __launch_bounds__(256, 6)
void tnrd_main(const float* __restrict__ u,
               const float* __restrict__ wf,    // filters [48][49]
               const float2* __restrict__ tab,  // phi tables [48][TP]
               float* __restrict__ part)
{
    constexpr int NGRP = NC / CPG;
    constexpr int NPASS = CPG / 2;
    __shared__ __align__(16) float u_s[UT * USTR];          //  9152 B
    __shared__ __align__(16) float phi_s[2][PT * PSTR];     // 13376 B

    const int tid = threadIdx.x;
    const int bx = blockIdx.x, by = blockIdx.y;
    const int b = blockIdx.z / NGRP, g = blockIdx.z % NGRP;
    const int c0g = g * CPG;

    // ---- stage u tile (6-halo, zero-padded incl. stride pad) ----
    const int uy0 = by * OT - 6, ux0 = bx * OT - 6;
    const float* ub = u + b * (HH * WW);
    for (int i = tid; i < UT * USTR; i += 256) {
        int r = i / USTR, c = i - r * USTR;
        int gy = uy0 + r, gx = ux0 + c;
        float v = 0.f;
        if (c < UT && (unsigned)gy < HH && (unsigned)gx < WW)
            v = ub[gy * WW + gx];
        u_s[i] = v;
    }
    __syncthreads();

    const int oy = tid >> 3;        // 0..31
    const int ox0 = (tid & 7) * 4;  // 0..28
    float o0 = 0.f, o1 = 0.f, o2 = 0.f, o3 = 0.f;
    const int py0 = by * OT - 3, px0 = bx * OT - 3;

    // ---- conv1 + RBF lerp for channel pair cp into planes bufA/bufB ----
    auto conv1_pass = [&](int cp, float* __restrict__ bufA,
                          float* __restrict__ bufB) {
        const float* wA = wf + (c0g + 2 * cp) * 49;   // block-uniform s_load
        const float* wB = wA + 49;
        const float2* tA = tab + (c0g + 2 * cp) * TP;     // global, L1-hot
        const float2* tB = tA + TP;
        // 380 items = 10 col-strips x 38 rows (column-major)
        for (int p = 0; p < 2; ++p) {
            const int gi = tid + p * 256;
            if (gi < PT * 10) {
                const int pr = gi % PT, pc = (gi / PT) * 4;
                float a0 = 0.f, a1 = 0.f, a2 = 0.f, a3 = 0.f;
                float b0 = 0.f, b1 = 0.f, b2 = 0.f, b3 = 0.f;
                const float* bptr = &u_s[pr * USTR + pc];

                // software pipeline: load row dy+1 before consuming row dy
                float4 c0 = *(const float4*)(bptr);
                float4 c1 = *(const float4*)(bptr + 4);
                float2 c2 = *(const float2*)(bptr + 8);
                #pragma unroll 1
                for (int dy = 0; dy < 6; ++dy) {
                    const float* nr = bptr + (dy + 1) * USTR;
                    float4 n0 = *(const float4*)(nr);
                    float4 n1 = *(const float4*)(nr + 4);
                    float2 n2 = *(const float2*)(nr + 8);
                    F1ROW(wA + dy * 7, wB + dy * 7, c0, c1, c2)
                    c0 = n0; c1 = n1; c2 = n2;
                }
                F1ROW(wA + 42, wB + 42, c0, c1, c2)   // epilogue dy=6

                // ---- 1-gather lerp; phi = 0 outside image ----
                const int gy = py0 + pr;
                const bool rowok = (unsigned)gy < HH;
                const bool ok0 = rowok && (unsigned)(px0 + pc + 0) < WW;
                const bool ok1 = rowok && (unsigned)(px0 + pc + 1) < WW;
                const bool ok2 = rowok && (unsigned)(px0 + pc + 2) < WW;
                const bool ok3 = rowok && (unsigned)(px0 + pc + 3) < WW;
                float pA0, pA1, pA2, pA3, pB0, pB1, pB2, pB3;
                LERP1(pA0, a0, tA) LERP1(pB0, b0, tB)
                LERP1(pA1, a1, tA) LERP1(pB1, b1, tB)
                LERP1(pA2, a2, tA) LERP1(pB2, b2, tB)
                LERP1(pA3, a3, tA) LERP1(pB3, b3, tB)
                pA0 = ok0 ? pA0 : 0.f;  pB0 = ok0 ? pB0 : 0.f;
                pA1 = ok1 ? pA1 : 0.f;  pB1 = ok1 ? pB1 : 0.f;
                pA2 = ok2 ? pA2 : 0.f;  pB2 = ok2 ? pB2 : 0.f;
                pA3 = ok3 ? pA3 : 0.f;  pB3 = ok3 ? pB3 : 0.f;
                *(float4*)(bufA + pr * PSTR + pc) =
                    make_float4(pA0, pA1, pA2, pA3);      // ds_write_b128
                *(float4*)(bufB + pr * PSTR + pc) =
                    make_float4(pB0, pB1, pB2, pB3);      // ds_write_b128
            }
        }
    };

    // single-buffered phi: conv1(p); sync; conv2(p); sync; ...
    #pragma unroll 1
    for (int pass = 0; pass < NPASS; ++pass) {
        conv1_pass(pass, phi_s[0], phi_s[1]);
        __syncthreads();

        // ---- conv2 accumulate pass's two channels (flipped weights) ----
        const float* wA = wf + (c0g + 2 * pass) * 49;
        const float* wB = wA + 49;
        const float* pA = phi_s[0];
        const float* pB = phi_s[1];
        for (int dy = 0; dy < 7; ++dy) {
            const float* rA = pA + (oy + dy) * PSTR + ox0;
            const float* rB = pB + (oy + dy) * PSTR + ox0;
            const float4 A0 = *(const float4*)(rA);
            const float4 A1 = *(const float4*)(rA + 4);
            const float2 A2 = *(const float2*)(rA + 8);
            const float4 B0 = *(const float4*)(rB);
            const float4 B1 = *(const float4*)(rB + 4);
            const float2 B2 = *(const float2*)(rB + 8);
            const float* wra = wA + (6 - dy) * 7;
            const float* wrb = wB + (6 - dy) * 7;
            C2STEP(6, A0.x, A0.y, A0.z, A0.w, B0.x, B0.y, B0.z, B0.w)
            C2STEP(5, A0.y, A0.z, A0.w, A1.x, B0.y, B0.z, B0.w, B1.x)
            C2STEP(4, A0.z, A0.w, A1.x, A1.y, B0.z, B0.w, B1.x, B1.y)
            C2STEP(3, A0.w, A1.x, A1.y, A1.z, B0.w, B1.x, B1.y, B1.z)
            C2STEP(2, A1.x, A1.y, A1.z, A1.w, B1.x, B1.y, B1.z, B1.w)
            C2STEP(1, A1.y, A1.z, A1.w, A2.x, B1.y, B1.z, B1.w, B2.x)
            C2STEP(0, A1.z, A1.w, A2.x, A2.y, B1.z, B1.w, B2.x, B2.y)
        }
        if (pass < NPASS - 1) __syncthreads();
    }

    const int gy = by * OT + oy, gx = bx * OT + ox0;
    float4 v4 = make_float4(o0, o1, o2, o3);
    *reinterpret_cast<float4*>(part + (size_t)g * NPIX + b * (HH * WW)
                               + gy * WW + gx) = v4;
}

template<int NGRP>
__global__ __launch_bounds__(256)
void combine_kernel(const float* __restrict__ u,
                    const float* __restrict__ f,
                    const float* __restrict__ lam,
                    const float* __restrict__ part,
                    float* __restrict__ out)
{
    int i = blockIdx.x * 256 + threadIdx.x;  // 512 blocks -> NPIX
    float d = 0.f;
    #pragma unroll
    for (int g = 0; g < NGRP; ++g) d += part[g * NPIX + i];
    float lv = lam[0];
    float uv = u[i];
    float fv = f[i];
    out[i] = uv - d - lv * (uv - fv);
}

extern "C" void kernel_launch(void* const* d_in, const int* in_sizes, int n_in,
                              void* d_out, int out_size, void* d_ws, size_t ws_size,
                              hipStream_t stream) {
    const float* u    = (const float*)d_in[0];
    const float* f    = (const float*)d_in[1];
    const float* filt = (const float*)d_in[2];
    const float* rbfw = (const float*)d_in[3];
    const float* lam  = (const float*)d_in[4];
    float* out = (float*)d_out;
    float* part = (float*)d_ws;
    // phi tables overlaid on d_out scratch (48*192 float2 = 18432 floats
    // <= 131072); combine_kernel fully overwrites d_out afterwards.
    float2* tabg = (float2*)d_out;

    tnrd_table<<<NC, 256, 0, stream>>>(rbfw, tabg);
    if (ws_size >= (size_t)12 * NPIX * sizeof(float)) {
        // 12 groups x 4ch: 1536 blocks = 6 blocks/CU (occupancy attack)
        tnrd_main<4><<<dim3(8, 8, 24), 256, 0, stream>>>(u, filt, tabg, part);
        combine_kernel<12><<<512, 256, 0, stream>>>(u, f, lam, part, out);
    } else {
        // fallback: 6 groups x 8ch, 768 blocks (r15 structure)
        tnrd_main<8><<<dim3(8, 8, 12), 256, 0, stream>>>(u, filt, tabg, part);
        combine_kernel<6><<<512, 256, 0, stream>>>(u, f, lam, part, out);
    }
}